// Round 7
// baseline (229.115 us; speedup 1.0000x reference)
//
#include <hip/hip_runtime.h>
#include <stdint.h>
#include <stddef.h>

#define S_LEN 2048
#define BATCH 2
#define HID 1024
#define NHEADS 16
#define HDIM 64

typedef __attribute__((ext_vector_type(8))) short short8;
typedef __attribute__((ext_vector_type(4))) short short4v;
typedef __attribute__((ext_vector_type(4))) float float4v;

#define MFMA32(a, b, c) __builtin_amdgcn_mfma_f32_16x16x32_bf16((a), (b), (c), 0, 0, 0)

__device__ __forceinline__ short f2bf(float f) {
  union { float f; uint32_t u; } v; v.f = f;
  uint32_t u = v.u;
  uint32_t r = (u + 0x7fffu + ((u >> 16) & 1u)) >> 16;
  return (short)(uint16_t)r;
}

// pack 4 fp32 -> 4 bf16 (round-half-up, v_perm)
__device__ __forceinline__ short4v pack_bf16x4(float4v v) {
  union { short4v s; uint32_t u[2]; } U;
  U.u[0] = __builtin_amdgcn_perm(__float_as_uint(v[1]) + 0x8000u,
                                 __float_as_uint(v[0]) + 0x8000u, 0x07060302u);
  U.u[1] = __builtin_amdgcn_perm(__float_as_uint(v[3]) + 0x8000u,
                                 __float_as_uint(v[2]) + 0x8000u, 0x07060302u);
  return U.s;
}

__device__ __forceinline__ void gl_lds16(const void* g, void* l) {
  __builtin_amdgcn_global_load_lds((const __attribute__((address_space(1))) void*)g,
                                   (__attribute__((address_space(3))) void*)l,
                                   16, 0, 0);
}

// ---------------- prep: cast X to bf16, build log2-domain mask bias ----------------
__global__ __launch_bounds__(256) void prep_cast(const float* __restrict__ x,
                                                 const int* __restrict__ mask,
                                                 short* __restrict__ xbf,
                                                 float* __restrict__ maskb) {
  int gid = blockIdx.x * 256 + threadIdx.x;
  const float4v* src = (const float4v*)x;
  float4v v = src[gid];
  short4v o;
  o[0] = f2bf(v[0]); o[1] = f2bf(v[1]); o[2] = f2bf(v[2]); o[3] = f2bf(v[3]);
  ((short4v*)xbf)[gid] = o;
  if (gid < BATCH * S_LEN) maskb[gid] = -14426.9504f * (float)mask[gid];
}

// ---------------- prep: transpose+cast the four weight matrices ----------------
__global__ __launch_bounds__(256) void prep_transpose(const float* __restrict__ w0,
                                                      const float* __restrict__ w1,
                                                      const float* __restrict__ w2,
                                                      const float* __restrict__ w3,
                                                      short* __restrict__ wt) {
  __shared__ short lds[64 * 66];
  int z = blockIdx.z;
  const float* w = (z == 0) ? w0 : (z == 1) ? w1 : (z == 2) ? w2 : w3;
  short* out = wt + (size_t)z * HID * HID;
  int k0 = blockIdx.x * 64, n0 = blockIdx.y * 64;
  int lane = threadIdx.x & 63, wrp = threadIdx.x >> 6;
#pragma unroll
  for (int i = 0; i < 16; i++) {
    int rr = wrp + i * 4;
    lds[lane * 66 + rr] = f2bf(w[(size_t)(k0 + rr) * HID + n0 + lane]);
  }
  __syncthreads();
#pragma unroll
  for (int i = 0; i < 16; i++) {
    int nn = wrp + i * 4;
    out[(size_t)(n0 + nn) * HID + k0 + lane] = lds[nn * 66 + lane];
  }
}

// ---------------- GEMM: C[M x N] = A[M x K] * Bt[N x K]^T + bias ----------------
// modes 0/1: Q/K (bf16 [b,h,s,d], wide stores via LDS gather)
// mode 2:    Vt (bf16 [b,h,d,s], wide stores via LDS transpose)
// mode 3:    fp32 row-major direct
#define VPS 136  // epilogue LDS row stride in shorts (272B, 16B-aligned)
template <int BM, int BN, bool EPI_LDS>
__global__ __launch_bounds__(256) void gemm_bt(const short* __restrict__ A,
                                               const short* __restrict__ WTbase,
                                               const float* __restrict__ bq,
                                               const float* __restrict__ bk,
                                               const float* __restrict__ bv,
                                               const float* __restrict__ bo,
                                               short* __restrict__ outQ,
                                               short* __restrict__ outK,
                                               short* __restrict__ outVt,
                                               float* __restrict__ outF,
                                               int mode_base) {
  constexpr int RI = BM / 32;
  constexpr int RJ = BN / 32;
  constexpr int LSZ1 = BM * 128 + BN * 128;
  constexpr int LSZ = (EPI_LDS && LSZ1 < 128 * VPS * 2) ? 128 * VPS * 2 : LSZ1;
  __shared__ __align__(16) char lds[LSZ];
  const int tid = threadIdx.x;
  const int lane = tid & 63, w = tid >> 6;
  const int wm = w & 1, wn = w >> 1;
  const int quad = lane >> 4, l15 = lane & 15;
  const int mode = mode_base + blockIdx.z;
  const short* Bt = WTbase + (size_t)mode * HID * HID;
  const float* bias = (mode == 0) ? bq : (mode == 1) ? bk : (mode == 2) ? bv : bo;
  const int m0 = blockIdx.x * BM, n0 = blockIdx.y * BN;

  float4v acc[RI][RJ];
#pragma unroll
  for (int i = 0; i < RI; i++)
#pragma unroll
    for (int j = 0; j < RJ; j++) acc[i][j] = (float4v)0.0f;

  for (int k0 = 0; k0 < HID; k0 += 64) {
    __syncthreads();
#pragma unroll
    for (int inst = 0; inst < BM / 32; inst++) {
      int p = inst * 256 + tid;
      int r = p >> 3;
      int c = (p & 7) ^ (r & 7);
      gl_lds16(A + (size_t)(m0 + r) * HID + k0 + c * 8, lds + p * 16);
    }
#pragma unroll
    for (int inst = 0; inst < BN / 32; inst++) {
      int p = inst * 256 + tid;
      int r = p >> 3;
      int c = (p & 7) ^ (r & 7);
      gl_lds16(Bt + (size_t)(n0 + r) * HID + k0 + c * 8, lds + BM * 128 + p * 16);
    }
    __syncthreads();
#pragma unroll
    for (int kk = 0; kk < 2; kk++) {
      short8 af[RI], bf[RJ];
#pragma unroll
      for (int i = 0; i < RI; i++) {
        int ra = wm * (BM / 2) + i * 16 + l15;
        af[i] = *(const short8*)(lds + ra * 128 + (((kk * 4 + quad) ^ (ra & 7)) * 16));
      }
#pragma unroll
      for (int j = 0; j < RJ; j++) {
        int rb = wn * (BN / 2) + j * 16 + l15;
        bf[j] = *(const short8*)(lds + BM * 128 + rb * 128 + (((kk * 4 + quad) ^ (rb & 7)) * 16));
      }
#pragma unroll
      for (int i = 0; i < RI; i++)
#pragma unroll
        for (int j = 0; j < RJ; j++)
          acc[i][j] = MFMA32(af[i], bf[j], acc[i][j]);
    }
  }

  if (EPI_LDS && mode < 3) {
    // all bf16 outputs go through LDS for wide coalesced stores
    short* eb = (short*)lds;
    __syncthreads();
#pragma unroll
    for (int j = 0; j < RJ; j++) {
      int nl = wn * (BN / 2) + j * 16 + l15;
      float bsv = bias[n0 + nl];
#pragma unroll
      for (int i = 0; i < RI; i++)
#pragma unroll
        for (int r = 0; r < 4; r++) {
          int ml = wm * (BM / 2) + i * 16 + quad * 4 + r;
          short u = f2bf(acc[i][j][r] + bsv);
          if (mode == 2) eb[nl * VPS + ml] = u;       // transpose: [n][m]
          else           eb[ml * VPS + nl] = u;       // gather:    [m][n]
        }
    }
    __syncthreads();
    int row = tid >> 1, half = tid & 1;
    const short* src = eb + row * VPS + half * 64;
    short* dst;
    if (mode == 2) {
      int n = n0 + row, h = n >> 6, d = n & 63;
      int b = m0 >> 11, sc = (m0 & 2047) + half * 64;
      dst = outVt + ((size_t)(b * NHEADS + h) * HDIM + d) * S_LEN + sc;
    } else {
      int b = m0 >> 11, s = (m0 & 2047) + row;
      int h = (n0 >> 6) + half;
      short* outp = (mode == 0) ? outQ : outK;
      dst = outp + ((size_t)(b * NHEADS + h) * S_LEN + s) * HDIM;
    }
#pragma unroll
    for (int c = 0; c < 8; c++)
      *(short8*)(dst + c * 8) = *(const short8*)(src + c * 8);
    return;
  }

#pragma unroll
  for (int i = 0; i < RI; i++) {
#pragma unroll
    for (int j = 0; j < RJ; j++) {
      int n = n0 + wn * (BN / 2) + j * 16 + l15;
      float bsv = bias[n];
#pragma unroll
      for (int r = 0; r < 4; r++) {
        int m = m0 + wm * (BM / 2) + i * 16 + quad * 4 + r;
        outF[(size_t)m * HID + n] = acc[i][j][r] + bsv;
      }
    }
  }
}

// ---------------- fused attention: 4 waves (2q x 2k), all-MFMA32, in-lane P ----
// grid (S/64, NH, B), block 256 = 4 waves: qh=w>>1 (32 queries), kh=w&1
// (64 keys of each 128-key tile). QK^T computed transposed (C = K·Q^T) so P's
// C-layout (row=key=quad*4+r, col=q=l15) packs IN-LANE into a 16x16x32
// A-frag via permuted key order k = quad*8 + (half*4 + r); V B-frags follow
// the same permutation (two 8B reads per granule pair from V^T rows).
#define ALDS_V 16384
#define ALDS_L 32768  // lrow partials: 4 waves x 32 floats
#define SCALE_L2E 0.18033688011f  // log2(e)/8

__device__ __forceinline__ float* buf_addr32(float* base, int row, int col) {
  // fp32 tile with row-stride 64, 16B-chunk xor swizzle on columns
  return base + row * 64 + ((((col >> 2) ^ (row & 15)) << 2) | (col & 3));
}

__global__ __launch_bounds__(256, 3) void attn(const short* __restrict__ Qb,
                                               const short* __restrict__ Kb,
                                               const short* __restrict__ Vt,
                                               const float* __restrict__ maskb,
                                               short* __restrict__ ctx) {
  __shared__ __align__(16) char lds[33792];  // K 16K | V^T 16K | lrow .5K
  const int tid = threadIdx.x, lane = tid & 63, w = tid >> 6;
  const int qh = w >> 1, kh = w & 1;
  const int quad = lane >> 4, l15 = lane & 15;
  const int h = blockIdx.y, b = blockIdx.z, bh = b * NHEADS + h;
  const short* Qh = Qb + (size_t)bh * S_LEN * HDIM;
  const short* Kh = Kb + (size_t)bh * S_LEN * HDIM;
  const short* Vh = Vt + (size_t)bh * HDIM * S_LEN;
  const float* mbase = maskb + b * S_LEN;
  const int qb0 = blockIdx.x * 64;

  // Q B-frags: wave's 2 query tiles (q = qb0 + qh*32 + nt*16 + l15)
  short8 qf[2][2];
#pragma unroll
  for (int nt = 0; nt < 2; nt++)
#pragma unroll
    for (int kk = 0; kk < 2; kk++)
      qf[nt][kk] = *(const short8*)(Qh + (size_t)(qb0 + qh * 32 + nt * 16 + l15) * HDIM + kk * 32 + quad * 8);

  float4v o[2][4];  // [q-tile][d-tile], C-layout row=q=quad*4+r, col=d=l15
#pragma unroll
  for (int nt = 0; nt < 2; nt++)
#pragma unroll
    for (int nd = 0; nd < 4; nd++) o[nt][nd] = (float4v)0.0f;
  float lp[2] = {0.0f, 0.0f};

  for (int kb = 0; kb < S_LEN; kb += 128) {
    __syncthreads();
#pragma unroll
    for (int inst = 0; inst < 4; inst++) {
      int p = inst * 256 + tid;
      int r = p >> 3, c = (p & 7) ^ (r & 7);
      gl_lds16(Kh + (size_t)(kb + r) * HDIM + c * 8, lds + p * 16);
      int rv = p >> 4, cv = (p & 15) ^ (rv & 7);
      gl_lds16(Vh + (size_t)rv * S_LEN + kb + cv * 8, lds + ALDS_V + p * 16);
    }
    __syncthreads();

    // QK^T + exp2 for the wave's 64 keys (4 x 16-key tiles), pack P in-lane
    union { short8 s8; short4v h4[2]; } ap[2][2];  // [key-group g][q-tile nt]
#pragma unroll
    for (int mt = 0; mt < 4; mt++) {
      int rk = kh * 64 + mt * 16 + l15;
      short8 ka0 = *(const short8*)(lds + rk * 128 + ((quad ^ (rk & 7)) * 16));
      short8 ka1 = *(const short8*)(lds + rk * 128 + (((4 + quad) ^ (rk & 7)) * 16));
      float4v mbv = *(const float4v*)(mbase + kb + kh * 64 + mt * 16 + quad * 4);
#pragma unroll
      for (int nt = 0; nt < 2; nt++) {
        float4v c = (float4v)0.0f;
        c = MFMA32(ka0, qf[nt][0], c);  // C[key][q]
        c = MFMA32(ka1, qf[nt][1], c);
        float4v ev;
#pragma unroll
        for (int r = 0; r < 4; r++) ev[r] = __builtin_amdgcn_exp2f(c[r] * SCALE_L2E + mbv[r]);
        lp[nt] += (ev[0] + ev[1]) + (ev[2] + ev[3]);
        ap[mt >> 1][nt].h4[mt & 1] = pack_bf16x4(ev);
      }
    }

    // V B-frags in the same permuted key order; PV via full-K MFMA32
#pragma unroll
    for (int g = 0; g < 2; g++) {
      int kgo = kh * 16 + g * 8;       // 8B-granule offset of this 32-key group
      int g0 = kgo + quad, g1 = g0 + 4;
      short8 vf;
#pragma unroll
      for (int nd = 0; nd < 4; nd++) {
        int rv = nd * 16 + l15;
        union { short8 s8; short4v h4[2]; } V;
        V.h4[0] = *(const short4v*)(lds + ALDS_V + rv * 256 + (((g0 >> 1) ^ (rv & 7)) * 16) + (g0 & 1) * 8);
        V.h4[1] = *(const short4v*)(lds + ALDS_V + rv * 256 + (((g1 >> 1) ^ (rv & 7)) * 16) + (g1 & 1) * 8);
        vf = V.s8;
#pragma unroll
        for (int nt = 0; nt < 2; nt++) o[nt][nd] = MFMA32(ap[g][nt].s8, vf, o[nt][nd]);
      }
    }
  }

  // ---- epilogue: 2-way key-half combine + normalize + wide stores ----
#pragma unroll
  for (int nt = 0; nt < 2; nt++) {
    lp[nt] += __shfl_xor(lp[nt], 16, 64);
    lp[nt] += __shfl_xor(lp[nt], 32, 64);  // per-q sums for q = nt*16+l15
  }
  float* lrowS = (float*)(lds + ALDS_L);
  __syncthreads();
  if (quad == 0) {
#pragma unroll
    for (int nt = 0; nt < 2; nt++) lrowS[w * 32 + nt * 16 + l15] = lp[nt];
  }
  float* pbuf = (float*)(lds + qh * 8192);  // 32x64 fp32 partial (in K region)
  if (kh == 1) {
#pragma unroll
    for (int nt = 0; nt < 2; nt++)
#pragma unroll
      for (int nd = 0; nd < 4; nd++)
#pragma unroll
        for (int r = 0; r < 4; r++)
          *buf_addr32(pbuf, nt * 16 + quad * 4 + r, nd * 16 + l15) = o[nt][nd][r];
  }
  __syncthreads();
  float* nbuf = (float*)(lds + ALDS_V);  // 64x64 fp32 normalized O
  if (kh == 0) {
#pragma unroll
    for (int nt = 0; nt < 2; nt++) {
#pragma unroll
      for (int r = 0; r < 4; r++) {
        int row32 = nt * 16 + quad * 4 + r;
        float ls = lrowS[(qh * 2) * 32 + row32] + lrowS[(qh * 2 + 1) * 32 + row32];
        float inv = 1.0f / ls;
#pragma unroll
        for (int nd = 0; nd < 4; nd++) {
          float val = (o[nt][nd][r] + *buf_addr32(pbuf, row32, nd * 16 + l15)) * inv;
          *buf_addr32(nbuf, qh * 32 + row32, nd * 16 + l15) = val;
        }
      }
    }
  }
  __syncthreads();
  // coalesced ctx store: thread covers (q = tid>>2, 16 d starting (tid&3)*16)
  {
    int q = tid >> 2, c0 = (tid & 3) * 16;
    float4v f0 = *(float4v*)buf_addr32(nbuf, q, c0);
    float4v f1 = *(float4v*)buf_addr32(nbuf, q, c0 + 4);
    float4v f2 = *(float4v*)buf_addr32(nbuf, q, c0 + 8);
    float4v f3 = *(float4v*)buf_addr32(nbuf, q, c0 + 12);
    union { short8 s8; short4v h4[2]; } R0, R1;
    R0.h4[0] = pack_bf16x4(f0); R0.h4[1] = pack_bf16x4(f1);
    R1.h4[0] = pack_bf16x4(f2); R1.h4[1] = pack_bf16x4(f3);
    short* dstp = ctx + (size_t)(b * S_LEN + qb0 + q) * HID + h * HDIM + c0;
    *(short8*)dstp = R0.s8;
    *(short8*)(dstp + 8) = R1.s8;
  }
}

extern "C" void kernel_launch(void* const* d_in, const int* in_sizes, int n_in,
                              void* d_out, int out_size, void* d_ws, size_t ws_size,
                              hipStream_t stream) {
  const float* hs = (const float*)d_in[0];
  const int* mask = (const int*)d_in[1];
  const float* Wq = (const float*)d_in[2];
  const float* bq = (const float*)d_in[3];
  const float* Wk = (const float*)d_in[4];
  const float* bk = (const float*)d_in[5];
  const float* Wv = (const float*)d_in[6];
  const float* bv = (const float*)d_in[7];
  const float* Wo = (const float*)d_in[8];
  const float* bo = (const float*)d_in[9];
  float* out = (float*)d_out;
  char* ws = (char*)d_ws;

  short* XBF = (short*)(ws);
  short* CTX = (short*)(ws);
  short* WT  = (short*)(ws + (size_t)(8u << 20));
  short* QB  = (short*)(ws + (size_t)(16u << 20));
  short* KB  = (short*)(ws + (size_t)(24u << 20));
  short* VTt = (short*)(ws + (size_t)(32u << 20));
  float* MB  = (float*)(ws + (size_t)(40u << 20));

  prep_cast<<<4096, 256, 0, stream>>>(hs, mask, XBF, MB);
  prep_transpose<<<dim3(16, 16, 4), 256, 0, stream>>>(Wq, Wk, Wv, Wo, WT);
  gemm_bt<128, 128, true><<<dim3(32, 8, 3), 256, 0, stream>>>(XBF, WT, bq, bk, bv, bo, QB, KB, VTt, nullptr, 0);
  attn<<<dim3(32, NHEADS, BATCH), 256, 0, stream>>>(QB, KB, VTt, MB, CTX);
  gemm_bt<64, 128, false><<<dim3(64, 8, 1), 256, 0, stream>>>(CTX, WT, bq, bk, bv, bo, nullptr, nullptr, nullptr, out, 3);
}

// Round 8
// 228.312 us; speedup vs baseline: 1.0035x; 1.0035x over previous
//
#include <hip/hip_runtime.h>
#include <stdint.h>
#include <stddef.h>

#define S_LEN 2048
#define BATCH 2
#define HID 1024
#define NHEADS 16
#define HDIM 64

typedef __attribute__((ext_vector_type(8))) short short8;
typedef __attribute__((ext_vector_type(4))) short short4v;
typedef __attribute__((ext_vector_type(4))) float float4v;

#define MFMA32(a, b, c) __builtin_amdgcn_mfma_f32_16x16x32_bf16((a), (b), (c), 0, 0, 0)

__device__ __forceinline__ short f2bf(float f) {
  union { float f; uint32_t u; } v; v.f = f;
  uint32_t u = v.u;
  uint32_t r = (u + 0x7fffu + ((u >> 16) & 1u)) >> 16;
  return (short)(uint16_t)r;
}

// pack 4 fp32 -> 4 bf16 (round-half-up, v_perm)
__device__ __forceinline__ short4v pack_bf16x4(float4v v) {
  union { short4v s; uint32_t u[2]; } U;
  U.u[0] = __builtin_amdgcn_perm(__float_as_uint(v[1]) + 0x8000u,
                                 __float_as_uint(v[0]) + 0x8000u, 0x07060302u);
  U.u[1] = __builtin_amdgcn_perm(__float_as_uint(v[3]) + 0x8000u,
                                 __float_as_uint(v[2]) + 0x8000u, 0x07060302u);
  return U.s;
}

__device__ __forceinline__ void gl_lds16(const void* g, void* l) {
  __builtin_amdgcn_global_load_lds((const __attribute__((address_space(1))) void*)g,
                                   (__attribute__((address_space(3))) void*)l,
                                   16, 0, 0);
}

// ---------------- prep: cast X to bf16, build log2-domain mask bias ----------------
__global__ __launch_bounds__(256) void prep_cast(const float* __restrict__ x,
                                                 const int* __restrict__ mask,
                                                 short* __restrict__ xbf,
                                                 float* __restrict__ maskb) {
  int gid = blockIdx.x * 256 + threadIdx.x;
  const float4v* src = (const float4v*)x;
  float4v v = src[gid];
  short4v o;
  o[0] = f2bf(v[0]); o[1] = f2bf(v[1]); o[2] = f2bf(v[2]); o[3] = f2bf(v[3]);
  ((short4v*)xbf)[gid] = o;
  if (gid < BATCH * S_LEN) maskb[gid] = -14426.9504f * (float)mask[gid];
}

// ---------------- prep: transpose+cast the four weight matrices ----------------
__global__ __launch_bounds__(256) void prep_transpose(const float* __restrict__ w0,
                                                      const float* __restrict__ w1,
                                                      const float* __restrict__ w2,
                                                      const float* __restrict__ w3,
                                                      short* __restrict__ wt) {
  __shared__ short lds[64 * 66];
  int z = blockIdx.z;
  const float* w = (z == 0) ? w0 : (z == 1) ? w1 : (z == 2) ? w2 : w3;
  short* out = wt + (size_t)z * HID * HID;
  int k0 = blockIdx.x * 64, n0 = blockIdx.y * 64;
  int lane = threadIdx.x & 63, wrp = threadIdx.x >> 6;
#pragma unroll
  for (int i = 0; i < 16; i++) {
    int rr = wrp + i * 4;
    lds[lane * 66 + rr] = f2bf(w[(size_t)(k0 + rr) * HID + n0 + lane]);
  }
  __syncthreads();
#pragma unroll
  for (int i = 0; i < 16; i++) {
    int nn = wrp + i * 4;
    out[(size_t)(n0 + nn) * HID + k0 + lane] = lds[nn * 66 + lane];
  }
}

// ---------------- GEMM: C[M x N] = A[M x K] * Bt[N x K]^T + bias ----------------
// modes 0/1/2: Q / K / Vt (bf16 attention layouts; Vt via LDS transpose). mode 3: fp32.
#define VPS 136  // Vt epilogue LDS row stride (shorts): 272B, 16B-aligned
template <int BM, int BN, bool TRANS_EP>
__global__ __launch_bounds__(256) void gemm_bt(const short* __restrict__ A,
                                               const short* __restrict__ WTbase,
                                               const float* __restrict__ bq,
                                               const float* __restrict__ bk,
                                               const float* __restrict__ bv,
                                               const float* __restrict__ bo,
                                               short* __restrict__ outQ,
                                               short* __restrict__ outK,
                                               short* __restrict__ outVt,
                                               float* __restrict__ outF,
                                               int mode_base) {
  constexpr int RI = BM / 32;
  constexpr int RJ = BN / 32;
  constexpr int LSZ1 = BM * 128 + BN * 128;
  constexpr int LSZ = (TRANS_EP && LSZ1 < 128 * VPS * 2) ? 128 * VPS * 2 : LSZ1;
  __shared__ __align__(16) char lds[LSZ];
  const int tid = threadIdx.x;
  const int lane = tid & 63, w = tid >> 6;
  const int wm = w & 1, wn = w >> 1;
  const int quad = lane >> 4, l15 = lane & 15;
  const int mode = mode_base + blockIdx.z;
  const short* Bt = WTbase + (size_t)mode * HID * HID;
  const float* bias = (mode == 0) ? bq : (mode == 1) ? bk : (mode == 2) ? bv : bo;
  const int m0 = blockIdx.x * BM, n0 = blockIdx.y * BN;

  float4v acc[RI][RJ];
#pragma unroll
  for (int i = 0; i < RI; i++)
#pragma unroll
    for (int j = 0; j < RJ; j++) acc[i][j] = (float4v)0.0f;

  for (int k0 = 0; k0 < HID; k0 += 64) {
    __syncthreads();
#pragma unroll
    for (int inst = 0; inst < BM / 32; inst++) {
      int p = inst * 256 + tid;
      int r = p >> 3;
      int c = (p & 7) ^ (r & 7);
      gl_lds16(A + (size_t)(m0 + r) * HID + k0 + c * 8, lds + p * 16);
    }
#pragma unroll
    for (int inst = 0; inst < BN / 32; inst++) {
      int p = inst * 256 + tid;
      int r = p >> 3;
      int c = (p & 7) ^ (r & 7);
      gl_lds16(Bt + (size_t)(n0 + r) * HID + k0 + c * 8, lds + BM * 128 + p * 16);
    }
    __syncthreads();
#pragma unroll
    for (int kk = 0; kk < 2; kk++) {
      short8 af[RI], bf[RJ];
#pragma unroll
      for (int i = 0; i < RI; i++) {
        int ra = wm * (BM / 2) + i * 16 + l15;
        af[i] = *(const short8*)(lds + ra * 128 + (((kk * 4 + quad) ^ (ra & 7)) * 16));
      }
#pragma unroll
      for (int j = 0; j < RJ; j++) {
        int rb = wn * (BN / 2) + j * 16 + l15;
        bf[j] = *(const short8*)(lds + BM * 128 + rb * 128 + (((kk * 4 + quad) ^ (rb & 7)) * 16));
      }
#pragma unroll
      for (int i = 0; i < RI; i++)
#pragma unroll
        for (int j = 0; j < RJ; j++)
          acc[i][j] = MFMA32(af[i], bf[j], acc[i][j]);
    }
  }

  if (TRANS_EP && mode == 2) {
    short* eb = (short*)lds;
    __syncthreads();
#pragma unroll
    for (int j = 0; j < RJ; j++) {
      int nl = wn * (BN / 2) + j * 16 + l15;
      float bsv = bias[n0 + nl];
#pragma unroll
      for (int i = 0; i < RI; i++)
#pragma unroll
        for (int r = 0; r < 4; r++) {
          int ml = wm * (BM / 2) + i * 16 + quad * 4 + r;
          eb[nl * VPS + ml] = f2bf(acc[i][j][r] + bsv);
        }
    }
    __syncthreads();
    int row = tid >> 1, half = tid & 1;
    int n = n0 + row, h = n >> 6, d = n & 63;
    int b = m0 >> 11, sc = (m0 & 2047) + half * 64;
    short* dst = outVt + ((size_t)(b * NHEADS + h) * HDIM + d) * S_LEN + sc;
    const short* src = eb + row * VPS + half * 64;
#pragma unroll
    for (int c = 0; c < 8; c++)
      *(short8*)(dst + c * 8) = *(const short8*)(src + c * 8);
    return;
  }

#pragma unroll
  for (int i = 0; i < RI; i++) {
#pragma unroll
    for (int j = 0; j < RJ; j++) {
      int n = n0 + wn * (BN / 2) + j * 16 + l15;
      float bsv = bias[n];
#pragma unroll
      for (int r = 0; r < 4; r++) {
        int m = m0 + wm * (BM / 2) + i * 16 + quad * 4 + r;
        float val = acc[i][j][r] + bsv;
        if (mode == 3) {
          outF[(size_t)m * HID + n] = val;
        } else {
          int b = m >> 11, s = m & 2047, h = n >> 6, d = n & 63;
          short u = f2bf(val);
          if (mode == 0)
            outQ[((size_t)(b * NHEADS + h) * S_LEN + s) * HDIM + d] = u;
          else
            outK[((size_t)(b * NHEADS + h) * S_LEN + s) * HDIM + d] = u;
        }
      }
    }
  }
}

// ---------------- fused attention: 128-query blocks, query-split waves ----------
// grid (S/128, NH, B), block 256 = 4 waves; wave w owns queries [w*32, w*32+32)
// COMPLETELY (no cross-wave O/l reduction). Per 128-key tile each wave sweeps
// all 128 keys: QK^T transposed (C = K·Q^T) so P's C-layout packs IN-LANE into
// 16x16x32 A-frags (permuted key order k = quad*8 + hf*4 + r); V B-frags use
// the same permutation. Doubling queries/block HALVES K/V staging traffic
// (532 -> 266 MB), attacking the L2/L3 staging-BW ceiling seen in r2/r3/r7.
#define ALDS_V 16384
#define ALDS_L 32768  // per-wave lrow: 4 waves x 32 floats
#define SCALE_L2E 0.18033688011f  // log2(e)/8

__device__ __forceinline__ float* buf_addr32(float* base, int row, int col) {
  // fp32 scratch, row stride 64, 16B-chunk xor swizzle on columns
  return base + row * 64 + ((((col >> 2) ^ (row & 15)) << 2) | (col & 3));
}

__global__ __launch_bounds__(256) void attn(const short* __restrict__ Qb,
                                            const short* __restrict__ Kb,
                                            const short* __restrict__ Vt,
                                            const float* __restrict__ maskb,
                                            short* __restrict__ ctx) {
  __shared__ __align__(16) char lds[33280];  // K 16K | V^T 16K | lrow 512B
  const int tid = threadIdx.x, lane = tid & 63, w = tid >> 6;
  const int quad = lane >> 4, l15 = lane & 15;
  const int h = blockIdx.y, b = blockIdx.z, bh = b * NHEADS + h;
  const short* Qh = Qb + (size_t)bh * S_LEN * HDIM;
  const short* Kh = Kb + (size_t)bh * S_LEN * HDIM;
  const short* Vh = Vt + (size_t)bh * HDIM * S_LEN;
  const float* mbase = maskb + b * S_LEN;
  const int qw = blockIdx.x * 128 + w * 32;  // wave's first query

  // Q B-frags for the wave's 2 query tiles (held in regs whole kernel)
  short8 qf[2][2];
#pragma unroll
  for (int nt = 0; nt < 2; nt++)
#pragma unroll
    for (int kk = 0; kk < 2; kk++)
      qf[nt][kk] = *(const short8*)(Qh + (size_t)(qw + nt * 16 + l15) * HDIM + kk * 32 + quad * 8);

  float4v o[2][4];  // C-layout: row=q=quad*4+r (+16nt), col=d=l15 (+16nd)
#pragma unroll
  for (int nt = 0; nt < 2; nt++)
#pragma unroll
    for (int nd = 0; nd < 4; nd++) o[nt][nd] = (float4v)0.0f;
  float lp[2] = {0.0f, 0.0f};

  for (int kb = 0; kb < S_LEN; kb += 128) {
    __syncthreads();
#pragma unroll
    for (int inst = 0; inst < 4; inst++) {
      int p = inst * 256 + tid;
      int r = p >> 3, c = (p & 7) ^ (r & 7);
      gl_lds16(Kh + (size_t)(kb + r) * HDIM + c * 8, lds + p * 16);
      int rv = p >> 4, cv = (p & 15) ^ (rv & 7);
      gl_lds16(Vh + (size_t)rv * S_LEN + kb + cv * 8, lds + ALDS_V + p * 16);
    }
    __syncthreads();

    // 4 key groups of 32; per group: QK^T + exp2 + in-lane pack, then PV
#pragma unroll
    for (int g = 0; g < 4; g++) {
      union { short8 s8; short4v h4[2]; } ap[2];
#pragma unroll
      for (int hf = 0; hf < 2; hf++) {
        int kt = g * 2 + hf;
        int rk = kt * 16 + l15;
        short8 ka0 = *(const short8*)(lds + rk * 128 + ((quad ^ (rk & 7)) * 16));
        short8 ka1 = *(const short8*)(lds + rk * 128 + (((4 + quad) ^ (rk & 7)) * 16));
        float4v mbv = *(const float4v*)(mbase + kb + kt * 16 + quad * 4);
#pragma unroll
        for (int nt = 0; nt < 2; nt++) {
          float4v c = (float4v)0.0f;
          c = MFMA32(ka0, qf[nt][0], c);  // C[key][q]
          c = MFMA32(ka1, qf[nt][1], c);
          float4v ev;
#pragma unroll
          for (int r = 0; r < 4; r++) ev[r] = __builtin_amdgcn_exp2f(c[r] * SCALE_L2E + mbv[r]);
          lp[nt] += (ev[0] + ev[1]) + (ev[2] + ev[3]);
          ap[nt].h4[hf] = pack_bf16x4(ev);
        }
      }
      // V B-frags, permuted key order; PV via full-K MFMA32
      int g0 = g * 8 + quad, g1 = g0 + 4;  // 8B granule indices in 256B rows
#pragma unroll
      for (int nd = 0; nd < 4; nd++) {
        int rv = nd * 16 + l15;
        union { short8 s8; short4v h4[2]; } V;
        V.h4[0] = *(const short4v*)(lds + ALDS_V + rv * 256 + (((g0 >> 1) ^ (rv & 7)) * 16) + (g0 & 1) * 8);
        V.h4[1] = *(const short4v*)(lds + ALDS_V + rv * 256 + (((g1 >> 1) ^ (rv & 7)) * 16) + (g1 & 1) * 8);
#pragma unroll
        for (int nt = 0; nt < 2; nt++) o[nt][nd] = MFMA32(ap[nt].s8, V.s8, o[nt][nd]);
      }
    }
  }

  // ---- epilogue: wave-private (queries owned outright) ----
#pragma unroll
  for (int nt = 0; nt < 2; nt++) {
    lp[nt] += __shfl_xor(lp[nt], 16, 64);
    lp[nt] += __shfl_xor(lp[nt], 32, 64);  // full sum for q = nt*16 + l15
  }
  float* lrowS = (float*)(lds + ALDS_L);
  if (quad == 0) {
#pragma unroll
    for (int nt = 0; nt < 2; nt++) lrowS[w * 32 + nt * 16 + l15] = lp[nt];
  }
  // re-read denominators indexed by the o-accumulator's row mapping (wave-local)
  float inv[2][4];
#pragma unroll
  for (int nt = 0; nt < 2; nt++) {
    float4v ls4 = *(const float4v*)&lrowS[w * 32 + nt * 16 + quad * 4];
#pragma unroll
    for (int r = 0; r < 4; r++) inv[nt][r] = 1.0f / ls4[r];
  }
  __syncthreads();  // all waves done reading K/V before scratch overwrite
  float* scr = (float*)(lds + w * 8192);  // wave-private 32x64 fp32
#pragma unroll
  for (int nt = 0; nt < 2; nt++)
#pragma unroll
    for (int nd = 0; nd < 4; nd++)
#pragma unroll
      for (int r = 0; r < 4; r++)
        *buf_addr32(scr, nt * 16 + quad * 4 + r, nd * 16 + l15) = o[nt][nd][r] * inv[nt][r];
  // coalesced-ish store: per lane 2 rows x 16 cols (16B segments)
#pragma unroll
  for (int s = 0; s < 2; s++) {
    int row = s * 16 + l15;
    float4v f0 = *(float4v*)buf_addr32(scr, row, quad * 16);
    float4v f1 = *(float4v*)buf_addr32(scr, row, quad * 16 + 4);
    float4v f2 = *(float4v*)buf_addr32(scr, row, quad * 16 + 8);
    float4v f3 = *(float4v*)buf_addr32(scr, row, quad * 16 + 12);
    union { short8 s8; short4v h4[2]; } R0, R1;
    R0.h4[0] = pack_bf16x4(f0); R0.h4[1] = pack_bf16x4(f1);
    R1.h4[0] = pack_bf16x4(f2); R1.h4[1] = pack_bf16x4(f3);
    short* dstp = ctx + (size_t)(b * S_LEN + qw + row) * HID + h * HDIM + quad * 16;
    *(short8*)dstp = R0.s8;
    *(short8*)(dstp + 8) = R1.s8;
  }
}

extern "C" void kernel_launch(void* const* d_in, const int* in_sizes, int n_in,
                              void* d_out, int out_size, void* d_ws, size_t ws_size,
                              hipStream_t stream) {
  const float* hs = (const float*)d_in[0];
  const int* mask = (const int*)d_in[1];
  const float* Wq = (const float*)d_in[2];
  const float* bq = (const float*)d_in[3];
  const float* Wk = (const float*)d_in[4];
  const float* bk = (const float*)d_in[5];
  const float* Wv = (const float*)d_in[6];
  const float* bv = (const float*)d_in[7];
  const float* Wo = (const float*)d_in[8];
  const float* bo = (const float*)d_in[9];
  float* out = (float*)d_out;
  char* ws = (char*)d_ws;

  short* XBF = (short*)(ws);
  short* CTX = (short*)(ws);
  short* WT  = (short*)(ws + (size_t)(8u << 20));
  short* QB  = (short*)(ws + (size_t)(16u << 20));
  short* KB  = (short*)(ws + (size_t)(24u << 20));
  short* VTt = (short*)(ws + (size_t)(32u << 20));
  float* MB  = (float*)(ws + (size_t)(40u << 20));

  prep_cast<<<4096, 256, 0, stream>>>(hs, mask, XBF, MB);
  prep_transpose<<<dim3(16, 16, 4), 256, 0, stream>>>(Wq, Wk, Wv, Wo, WT);
  gemm_bt<128, 128, true><<<dim3(32, 8, 3), 256, 0, stream>>>(XBF, WT, bq, bk, bv, bo, QB, KB, VTt, nullptr, 0);
  attn<<<dim3(16, NHEADS, BATCH), 256, 0, stream>>>(QB, KB, VTt, MB, CTX);
  gemm_bt<64, 128, false><<<dim3(64, 8, 1), 256, 0, stream>>>(CTX, WT, bq, bk, bv, bo, nullptr, nullptr, nullptr, out, 3);
}

// Round 9
// 221.089 us; speedup vs baseline: 1.0363x; 1.0327x over previous
//
#include <hip/hip_runtime.h>
#include <stdint.h>
#include <stddef.h>

#define S_LEN 2048
#define BATCH 2
#define HID 1024
#define NHEADS 16
#define HDIM 64

typedef __attribute__((ext_vector_type(8))) short short8;
typedef __attribute__((ext_vector_type(4))) short short4v;
typedef __attribute__((ext_vector_type(4))) float float4v;

#define MFMA32(a, b, c) __builtin_amdgcn_mfma_f32_16x16x32_bf16((a), (b), (c), 0, 0, 0)

#if __has_builtin(__builtin_amdgcn_mfma_f32_16x16x16_bf16)
#define MFMA16(a, b, c) __builtin_amdgcn_mfma_f32_16x16x16_bf16((a), (b), (c), 0, 0, 0)
#elif __has_builtin(__builtin_amdgcn_mfma_f32_16x16x16bf16_1k)
#define MFMA16(a, b, c) __builtin_amdgcn_mfma_f32_16x16x16bf16_1k((a), (b), (c), 0, 0, 0)
#else
static __device__ __forceinline__ float4v mfma16_asm(short4v a, short4v b, float4v c) {
  asm volatile("v_mfma_f32_16x16x16_bf16 %0, %1, %2, %0" : "+v"(c) : "v"(a), "v"(b));
  return c;
}
#define MFMA16(a, b, c) mfma16_asm((a), (b), (c))
#endif

#define SCALE_L2E 0.18033688011f  // log2(e)/8 — folded into K at GEMM epilogue

__device__ __forceinline__ short f2bf(float f) {
  union { float f; uint32_t u; } v; v.f = f;
  uint32_t u = v.u;
  uint32_t r = (u + 0x7fffu + ((u >> 16) & 1u)) >> 16;
  return (short)(uint16_t)r;
}

// pack 4 fp32 -> 4 bf16 (round-half-up, v_perm; A-frag k=quad*4+j order)
__device__ __forceinline__ short4v pack_bf16x4(float4v v) {
  union { short4v s; uint32_t u[2]; } U;
  U.u[0] = __builtin_amdgcn_perm(__float_as_uint(v[1]) + 0x8000u,
                                 __float_as_uint(v[0]) + 0x8000u, 0x07060302u);
  U.u[1] = __builtin_amdgcn_perm(__float_as_uint(v[3]) + 0x8000u,
                                 __float_as_uint(v[2]) + 0x8000u, 0x07060302u);
  return U.s;
}

__device__ __forceinline__ void gl_lds16(const void* g, void* l) {
  __builtin_amdgcn_global_load_lds((const __attribute__((address_space(1))) void*)g,
                                   (__attribute__((address_space(3))) void*)l,
                                   16, 0, 0);
}

// ---------------- merged prep: weight transposes (z<4) + X cast / mask (z==4) ----
__global__ __launch_bounds__(256) void prep(const float* __restrict__ x,
                                            const int* __restrict__ mask,
                                            const float* __restrict__ w0,
                                            const float* __restrict__ w1,
                                            const float* __restrict__ w2,
                                            const float* __restrict__ w3,
                                            short* __restrict__ xbf,
                                            float* __restrict__ maskb,
                                            short* __restrict__ wt) {
  int z = blockIdx.z;
  if (z == 4) {
    // cast X (4.19M floats) + mask bias: 256 blocks x 16 float4/thread
    int blk = blockIdx.y * 16 + blockIdx.x;
    const float4v* src = (const float4v*)x;
#pragma unroll
    for (int i = 0; i < 16; i++) {
      int gid = (blk * 16 + i) * 256 + threadIdx.x;
      float4v v = src[gid];
      short4v o;
      o[0] = f2bf(v[0]); o[1] = f2bf(v[1]); o[2] = f2bf(v[2]); o[3] = f2bf(v[3]);
      ((short4v*)xbf)[gid] = o;
      if (gid < BATCH * S_LEN) maskb[gid] = -14426.9504f * (float)mask[gid];
    }
    return;
  }
  __shared__ short lds[64 * 66];
  const float* w = (z == 0) ? w0 : (z == 1) ? w1 : (z == 2) ? w2 : w3;
  short* out = wt + (size_t)z * HID * HID;
  int k0 = blockIdx.x * 64, n0 = blockIdx.y * 64;
  int lane = threadIdx.x & 63, wrp = threadIdx.x >> 6;
#pragma unroll
  for (int i = 0; i < 16; i++) {
    int rr = wrp + i * 4;
    lds[lane * 66 + rr] = f2bf(w[(size_t)(k0 + rr) * HID + n0 + lane]);
  }
  __syncthreads();
#pragma unroll
  for (int i = 0; i < 16; i++) {
    int nn = wrp + i * 4;
    out[(size_t)(n0 + nn) * HID + k0 + lane] = lds[nn * 66 + lane];
  }
}

// ---------------- GEMM: C[M x N] = A[M x K] * Bt[N x K]^T + bias ----------------
// mode 0: Q (bf16 [b,h,s,d]); mode 1: K pre-scaled by log2e/8 (bf16 [b,h,s,d]);
// mode 2: Vt (bf16 [b,h,d,s] via LDS transpose); mode 3: fp32 row-major.
#define VPS 136  // Vt epilogue LDS row stride (shorts): 272B, 16B-aligned
template <int BM, int BN, bool TRANS_EP>
__global__ __launch_bounds__(256) void gemm_bt(const short* __restrict__ A,
                                               const short* __restrict__ WTbase,
                                               const float* __restrict__ bq,
                                               const float* __restrict__ bk,
                                               const float* __restrict__ bv,
                                               const float* __restrict__ bo,
                                               short* __restrict__ outQ,
                                               short* __restrict__ outK,
                                               short* __restrict__ outVt,
                                               float* __restrict__ outF,
                                               int mode_base) {
  constexpr int RI = BM / 32;
  constexpr int RJ = BN / 32;
  constexpr int LSZ1 = BM * 128 + BN * 128;
  constexpr int LSZ = (TRANS_EP && LSZ1 < 128 * VPS * 2) ? 128 * VPS * 2 : LSZ1;
  __shared__ __align__(16) char lds[LSZ];
  const int tid = threadIdx.x;
  const int lane = tid & 63, w = tid >> 6;
  const int wm = w & 1, wn = w >> 1;
  const int quad = lane >> 4, l15 = lane & 15;
  const int mode = mode_base + blockIdx.z;
  const short* Bt = WTbase + (size_t)mode * HID * HID;
  const float* bias = (mode == 0) ? bq : (mode == 1) ? bk : (mode == 2) ? bv : bo;
  const int m0 = blockIdx.x * BM, n0 = blockIdx.y * BN;

  float4v acc[RI][RJ];
#pragma unroll
  for (int i = 0; i < RI; i++)
#pragma unroll
    for (int j = 0; j < RJ; j++) acc[i][j] = (float4v)0.0f;

  for (int k0 = 0; k0 < HID; k0 += 64) {
    __syncthreads();
#pragma unroll
    for (int inst = 0; inst < BM / 32; inst++) {
      int p = inst * 256 + tid;
      int r = p >> 3;
      int c = (p & 7) ^ (r & 7);
      gl_lds16(A + (size_t)(m0 + r) * HID + k0 + c * 8, lds + p * 16);
    }
#pragma unroll
    for (int inst = 0; inst < BN / 32; inst++) {
      int p = inst * 256 + tid;
      int r = p >> 3;
      int c = (p & 7) ^ (r & 7);
      gl_lds16(Bt + (size_t)(n0 + r) * HID + k0 + c * 8, lds + BM * 128 + p * 16);
    }
    __syncthreads();
#pragma unroll
    for (int kk = 0; kk < 2; kk++) {
      short8 af[RI], bf[RJ];
#pragma unroll
      for (int i = 0; i < RI; i++) {
        int ra = wm * (BM / 2) + i * 16 + l15;
        af[i] = *(const short8*)(lds + ra * 128 + (((kk * 4 + quad) ^ (ra & 7)) * 16));
      }
#pragma unroll
      for (int j = 0; j < RJ; j++) {
        int rb = wn * (BN / 2) + j * 16 + l15;
        bf[j] = *(const short8*)(lds + BM * 128 + rb * 128 + (((kk * 4 + quad) ^ (rb & 7)) * 16));
      }
#pragma unroll
      for (int i = 0; i < RI; i++)
#pragma unroll
        for (int j = 0; j < RJ; j++)
          acc[i][j] = MFMA32(af[i], bf[j], acc[i][j]);
    }
  }

  if (TRANS_EP && mode == 2) {
    short* eb = (short*)lds;
    __syncthreads();
#pragma unroll
    for (int j = 0; j < RJ; j++) {
      int nl = wn * (BN / 2) + j * 16 + l15;
      float bsv = bias[n0 + nl];
#pragma unroll
      for (int i = 0; i < RI; i++)
#pragma unroll
        for (int r = 0; r < 4; r++) {
          int ml = wm * (BM / 2) + i * 16 + quad * 4 + r;
          eb[nl * VPS + ml] = f2bf(acc[i][j][r] + bsv);
        }
    }
    __syncthreads();
    int row = tid >> 1, half = tid & 1;
    int n = n0 + row, h = n >> 6, d = n & 63;
    int b = m0 >> 11, sc = (m0 & 2047) + half * 64;
    short* dst = outVt + ((size_t)(b * NHEADS + h) * HDIM + d) * S_LEN + sc;
    const short* src = eb + row * VPS + half * 64;
#pragma unroll
    for (int c = 0; c < 8; c++)
      *(short8*)(dst + c * 8) = *(const short8*)(src + c * 8);
    return;
  }

#pragma unroll
  for (int i = 0; i < RI; i++) {
#pragma unroll
    for (int j = 0; j < RJ; j++) {
      int n = n0 + wn * (BN / 2) + j * 16 + l15;
      float bsv = bias[n];
#pragma unroll
      for (int r = 0; r < 4; r++) {
        int m = m0 + wm * (BM / 2) + i * 16 + quad * 4 + r;
        float val = acc[i][j][r] + bsv;
        if (mode == 3) {
          outF[(size_t)m * HID + n] = val;
        } else {
          int b = m >> 11, s = m & 2047, h = n >> 6, d = n & 63;
          if (mode == 1) val *= SCALE_L2E;  // pre-scale K: exp2 arg = dot + maskbias
          short u = f2bf(val);
          if (mode == 0)
            outQ[((size_t)(b * NHEADS + h) * S_LEN + s) * HDIM + d] = u;
          else
            outK[((size_t)(b * NHEADS + h) * S_LEN + s) * HDIM + d] = u;
        }
      }
    }
  }
}

// ---------------- fused attention (r3 structure): key-split waves ----------------
// grid (S/64, NH, B), block 256 = 4 waves. Block owns 64 queries; per 128-key
// tile wave w handles keys [w*32, w*32+32). QK^T computed transposed
// (C=K*Q^T) so the 16x16 C-layout IS the 16x16x16 A-layout of P for PV.
// K is pre-scaled by log2e/8 and the accumulator is INITIALIZED with the mask
// bias, so post-MFMA softmax is a bare v_exp_f32 per element.
#define ALDS_K 0       // 16KB: K tile [128 keys][64 d] bf16, 16B chunks xor (r&7)
#define ALDS_V 16384   // 16KB: V^T tile [64 d][128 keys] bf16, 16B chunks xor (r&7)
#define ALDS_M 32768   // 8KB: mask bias fp32 [2048] (reused for lrow partials at end)

__device__ __forceinline__ float* buf_addr(float* base, int row, int col) {
  return base + row * 64 + ((((col >> 2) ^ (row & 15)) << 2) | (col & 3));
}

__global__ __launch_bounds__(256, 2) void attn(const short* __restrict__ Qb,
                                               const short* __restrict__ Kb,
                                               const short* __restrict__ Vt,
                                               const float* __restrict__ maskb,
                                               short* __restrict__ ctx) {
  __shared__ __align__(16) char lds[40960];
  const int tid = threadIdx.x, lane = tid & 63, w = tid >> 6;
  const int quad = lane >> 4, l15 = lane & 15;
  const int h = blockIdx.y, b = blockIdx.z, bh = b * NHEADS + h;
  const short* Qh = Qb + (size_t)bh * S_LEN * HDIM;
  const short* Kh = Kb + (size_t)bh * S_LEN * HDIM;
  const short* Vh = Vt + (size_t)bh * HDIM * S_LEN;
  const float* mbase = maskb + b * S_LEN;
  const int qb0 = blockIdx.x * 64;
  const int kw = w * 32;

  // stage mask bias (8KB) once; drained by the first in-loop barrier
#pragma unroll
  for (int inst = 0; inst < 2; inst++) {
    int p = inst * 256 + tid;
    gl_lds16(mbase + p * 4, lds + ALDS_M + p * 16);
  }

  // Q B-frags for all 4 query tiles (held in regs whole kernel)
  short8 qf[4][2];
#pragma unroll
  for (int nt = 0; nt < 4; nt++)
#pragma unroll
    for (int kk = 0; kk < 2; kk++)
      qf[nt][kk] = *(const short8*)(Qh + (size_t)(qb0 + nt * 16 + l15) * HDIM + kk * 32 + quad * 8);

  float4v o[4][4];
#pragma unroll
  for (int nt = 0; nt < 4; nt++)
#pragma unroll
    for (int nd = 0; nd < 4; nd++) o[nt][nd] = (float4v)0.0f;
  float lp[4] = {0.0f, 0.0f, 0.0f, 0.0f};

  for (int kb = 0; kb < S_LEN; kb += 128) {
    __syncthreads();
#pragma unroll
    for (int inst = 0; inst < 4; inst++) {
      int p = inst * 256 + tid;
      int r = p >> 3, c = (p & 7) ^ (r & 7);
      gl_lds16(Kh + (size_t)(kb + r) * HDIM + c * 8, lds + ALDS_K + p * 16);
      int rv = p >> 4, cv = (p & 15) ^ (rv & 7);
      gl_lds16(Vh + (size_t)rv * S_LEN + kb + cv * 8, lds + ALDS_V + p * 16);
    }
    __syncthreads();

    // V B-frags (16x16x16): n=d=l15+16nd, k=key=kw+mt*16+quad*4+j
    short4v bvf[2][4];
#pragma unroll
    for (int mt = 0; mt < 2; mt++) {
      int g = (kw >> 2) + mt * 4 + quad;
      int gc = g >> 1, sub = g & 1;
#pragma unroll
      for (int nd = 0; nd < 4; nd++) {
        int rv = nd * 16 + l15;
        bvf[mt][nd] = *(const short4v*)(lds + ALDS_V + rv * 256 + ((gc ^ (rv & 7)) * 16) + sub * 8);
      }
    }

#pragma unroll
    for (int mt = 0; mt < 2; mt++) {
      int rk = kw + mt * 16 + l15;
      short8 ka0 = *(const short8*)(lds + ALDS_K + rk * 128 + ((quad ^ (rk & 7)) * 16));
      short8 ka1 = *(const short8*)(lds + ALDS_K + rk * 128 + (((4 + quad) ^ (rk & 7)) * 16));
      float4v mbv = *(const float4v*)(lds + ALDS_M + (kb + kw + mt * 16) * 4 + quad * 16);
#pragma unroll
      for (int nt = 0; nt < 4; nt++) {
        float4v c = mbv;  // acc init = mask bias (exp2 domain); K pre-scaled
        c = MFMA32(ka0, qf[nt][0], c);  // C[key][q]
        c = MFMA32(ka1, qf[nt][1], c);
        float4v ev;
#pragma unroll
        for (int r = 0; r < 4; r++) ev[r] = __builtin_amdgcn_exp2f(c[r]);
        lp[nt] += (ev[0] + ev[1]) + (ev[2] + ev[3]);
        short4v ap = pack_bf16x4(ev);
#pragma unroll
        for (int nd = 0; nd < 4; nd++) o[nt][nd] = MFMA16(ap, bvf[mt][nd], o[nt][nd]);
      }
    }
  }

  // ---- epilogue: cross-wave O + lrow reduction through staging LDS ----
#pragma unroll
  for (int nt = 0; nt < 4; nt++) {
    lp[nt] += __shfl_xor(lp[nt], 16, 64);
    lp[nt] += __shfl_xor(lp[nt], 32, 64);
  }
  __syncthreads();
  float* buf0 = (float*)(lds + ALDS_K);
  float* buf1 = (float*)(lds + ALDS_V);
  float* lrowS = (float*)(lds + ALDS_M);
  if (quad == 0) {
#pragma unroll
    for (int nt = 0; nt < 4; nt++) lrowS[w * 64 + nt * 16 + l15] = lp[nt];
  }
  if (w & 1) {
    float* dst = (w == 1) ? buf0 : buf1;
#pragma unroll
    for (int nt = 0; nt < 4; nt++)
#pragma unroll
      for (int nd = 0; nd < 4; nd++)
#pragma unroll
        for (int r = 0; r < 4; r++)
          *buf_addr(dst, nt * 16 + quad * 4 + r, nd * 16 + l15) = o[nt][nd][r];
  }
  __syncthreads();
  if (!(w & 1)) {
    float* srcb = (w == 0) ? buf0 : buf1;
#pragma unroll
    for (int nt = 0; nt < 4; nt++)
#pragma unroll
      for (int nd = 0; nd < 4; nd++)
#pragma unroll
        for (int r = 0; r < 4; r++) {
          float* p = buf_addr(srcb, nt * 16 + quad * 4 + r, nd * 16 + l15);
          *p = *p + o[nt][nd][r];
        }
  }
  __syncthreads();
  int row = w * 16 + l15;
  float ls = lrowS[row] + lrowS[64 + row] + lrowS[128 + row] + lrowS[192 + row];
  float inv = 1.0f / ls;
  short* dstp = ctx + ((size_t)(b * S_LEN + qb0 + row) * HID + h * HDIM + quad * 16);
#pragma unroll
  for (int half = 0; half < 2; half++) {
    int c0 = quad * 16 + half * 8;
    float4v x0 = *(float4v*)buf_addr(buf0, row, c0);
    float4v x1 = *(float4v*)buf_addr(buf0, row, c0 + 4);
    float4v y0 = *(float4v*)buf_addr(buf1, row, c0);
    float4v y1 = *(float4v*)buf_addr(buf1, row, c0 + 4);
    union { short8 s; short4v h[2]; } R;
    float4v s0, s1;
#pragma unroll
    for (int i = 0; i < 4; i++) { s0[i] = (x0[i] + y0[i]) * inv; s1[i] = (x1[i] + y1[i]) * inv; }
    R.h[0] = pack_bf16x4(s0);
    R.h[1] = pack_bf16x4(s1);
    *(short8*)(dstp + half * 8) = R.s;
  }
}

extern "C" void kernel_launch(void* const* d_in, const int* in_sizes, int n_in,
                              void* d_out, int out_size, void* d_ws, size_t ws_size,
                              hipStream_t stream) {
  const float* hs = (const float*)d_in[0];
  const int* mask = (const int*)d_in[1];
  const float* Wq = (const float*)d_in[2];
  const float* bq = (const float*)d_in[3];
  const float* Wk = (const float*)d_in[4];
  const float* bk = (const float*)d_in[5];
  const float* Wv = (const float*)d_in[6];
  const float* bv = (const float*)d_in[7];
  const float* Wo = (const float*)d_in[8];
  const float* bo = (const float*)d_in[9];
  float* out = (float*)d_out;
  char* ws = (char*)d_ws;

  short* XBF = (short*)(ws);
  short* CTX = (short*)(ws);
  short* WT  = (short*)(ws + (size_t)(8u << 20));
  short* QB  = (short*)(ws + (size_t)(16u << 20));
  short* KB  = (short*)(ws + (size_t)(24u << 20));
  short* VTt = (short*)(ws + (size_t)(32u << 20));
  float* MB  = (float*)(ws + (size_t)(40u << 20));

  prep<<<dim3(16, 16, 5), 256, 0, stream>>>(hs, mask, Wq, Wk, Wv, Wo, XBF, MB, WT);
  gemm_bt<128, 128, true><<<dim3(32, 8, 3), 256, 0, stream>>>(XBF, WT, bq, bk, bv, bo, QB, KB, VTt, nullptr, 0);
  attn<<<dim3(32, NHEADS, BATCH), 256, 0, stream>>>(QB, KB, VTt, MB, CTX);
  gemm_bt<64, 128, false><<<dim3(64, 8, 1), 256, 0, stream>>>(CTX, WT, bq, bk, bv, bo, nullptr, nullptr, nullptr, out, 3);
}

// Round 10
// 203.645 us; speedup vs baseline: 1.1251x; 1.0857x over previous
//
#include <hip/hip_runtime.h>
#include <stdint.h>
#include <stddef.h>

#define S_LEN 2048
#define BATCH 2
#define HID 1024
#define NHEADS 16
#define HDIM 64

typedef __attribute__((ext_vector_type(8))) short short8;
typedef __attribute__((ext_vector_type(4))) short short4v;
typedef __attribute__((ext_vector_type(4))) float float4v;

#define MFMA32(a, b, c) __builtin_amdgcn_mfma_f32_16x16x32_bf16((a), (b), (c), 0, 0, 0)

#if __has_builtin(__builtin_amdgcn_mfma_f32_16x16x16_bf16)
#define MFMA16(a, b, c) __builtin_amdgcn_mfma_f32_16x16x16_bf16((a), (b), (c), 0, 0, 0)
#elif __has_builtin(__builtin_amdgcn_mfma_f32_16x16x16bf16_1k)
#define MFMA16(a, b, c) __builtin_amdgcn_mfma_f32_16x16x16bf16_1k((a), (b), (c), 0, 0, 0)
#else
static __device__ __forceinline__ float4v mfma16_asm(short4v a, short4v b, float4v c) {
  asm volatile("v_mfma_f32_16x16x16_bf16 %0, %1, %2, %0" : "+v"(c) : "v"(a), "v"(b));
  return c;
}
#define MFMA16(a, b, c) mfma16_asm((a), (b), (c))
#endif

#define SCALE_L2E 0.18033688011f  // log2(e)/8 — folded into K at GEMM epilogue

__device__ __forceinline__ short f2bf(float f) {
  union { float f; uint32_t u; } v; v.f = f;
  uint32_t u = v.u;
  uint32_t r = (u + 0x7fffu + ((u >> 16) & 1u)) >> 16;
  return (short)(uint16_t)r;
}

// pack 4 fp32 -> 4 bf16 (round-half-up, v_perm; A-frag k=quad*4+j order)
__device__ __forceinline__ short4v pack_bf16x4(float4v v) {
  union { short4v s; uint32_t u[2]; } U;
  U.u[0] = __builtin_amdgcn_perm(__float_as_uint(v[1]) + 0x8000u,
                                 __float_as_uint(v[0]) + 0x8000u, 0x07060302u);
  U.u[1] = __builtin_amdgcn_perm(__float_as_uint(v[3]) + 0x8000u,
                                 __float_as_uint(v[2]) + 0x8000u, 0x07060302u);
  return U.s;
}

__device__ __forceinline__ void gl_lds16(const void* g, void* l) {
  __builtin_amdgcn_global_load_lds((const __attribute__((address_space(1))) void*)g,
                                   (__attribute__((address_space(3))) void*)l,
                                   16, 0, 0);
}

// ---------------- prep: cast X to bf16, build log2-domain mask bias ----------------
__global__ __launch_bounds__(256) void prep_cast(const float* __restrict__ x,
                                                 const int* __restrict__ mask,
                                                 short* __restrict__ xbf,
                                                 float* __restrict__ maskb) {
  int gid = blockIdx.x * 256 + threadIdx.x;
  const float4v* src = (const float4v*)x;
  float4v v = src[gid];
  short4v o;
  o[0] = f2bf(v[0]); o[1] = f2bf(v[1]); o[2] = f2bf(v[2]); o[3] = f2bf(v[3]);
  ((short4v*)xbf)[gid] = o;
  if (gid < BATCH * S_LEN) maskb[gid] = -14426.9504f * (float)mask[gid];
}

// ---------------- prep: transpose+cast the four weight matrices ----------------
__global__ __launch_bounds__(256) void prep_transpose(const float* __restrict__ w0,
                                                      const float* __restrict__ w1,
                                                      const float* __restrict__ w2,
                                                      const float* __restrict__ w3,
                                                      short* __restrict__ wt) {
  __shared__ short lds[64 * 66];
  int z = blockIdx.z;
  const float* w = (z == 0) ? w0 : (z == 1) ? w1 : (z == 2) ? w2 : w3;
  short* out = wt + (size_t)z * HID * HID;
  int k0 = blockIdx.x * 64, n0 = blockIdx.y * 64;
  int lane = threadIdx.x & 63, wrp = threadIdx.x >> 6;
#pragma unroll
  for (int i = 0; i < 16; i++) {
    int rr = wrp + i * 4;
    lds[lane * 66 + rr] = f2bf(w[(size_t)(k0 + rr) * HID + n0 + lane]);
  }
  __syncthreads();
#pragma unroll
  for (int i = 0; i < 16; i++) {
    int nn = wrp + i * 4;
    out[(size_t)(n0 + nn) * HID + k0 + lane] = lds[nn * 66 + lane];
  }
}

// ---------------- GEMM: C[M x N] = A[M x K] * Bt[N x K]^T + bias ----------------
// mode 0: Q (bf16 [b,h,s,d]); mode 1: K pre-scaled by log2e/8 (bf16 [b,h,s,d]);
// mode 2: Vt (bf16 [b,h,d,s] via LDS transpose); mode 3: fp32 row-major.
// DBUF: raw-barrier double-buffered staging — next tile's global_load_lds stays
// in flight across the barrier (vmcnt(8), never 0 until last iter).
#define VPS 136  // Vt epilogue LDS row stride (shorts): 272B, 16B-aligned
template <int BM, int BN, bool TRANS_EP, bool DBUF>
__global__ __launch_bounds__(256) void gemm_bt(const short* __restrict__ A,
                                               const short* __restrict__ WTbase,
                                               const float* __restrict__ bq,
                                               const float* __restrict__ bk,
                                               const float* __restrict__ bv,
                                               const float* __restrict__ bo,
                                               short* __restrict__ outQ,
                                               short* __restrict__ outK,
                                               short* __restrict__ outVt,
                                               float* __restrict__ outF,
                                               int mode_base) {
  constexpr int RI = BM / 32;
  constexpr int RJ = BN / 32;
  constexpr int TILE = BM * 128 + BN * 128;  // one staging tile (A+B)
  constexpr int LSZ1 = DBUF ? TILE * 2 : TILE;
  constexpr int LSZ = (TRANS_EP && LSZ1 < 128 * VPS * 2) ? 128 * VPS * 2 : LSZ1;
  __shared__ __align__(16) char lds[LSZ];
  const int tid = threadIdx.x;
  const int lane = tid & 63, w = tid >> 6;
  const int wm = w & 1, wn = w >> 1;
  const int quad = lane >> 4, l15 = lane & 15;
  const int mode = mode_base + blockIdx.z;
  const short* Bt = WTbase + (size_t)mode * HID * HID;
  const float* bias = (mode == 0) ? bq : (mode == 1) ? bk : (mode == 2) ? bv : bo;
  const int m0 = blockIdx.x * BM, n0 = blockIdx.y * BN;

  float4v acc[RI][RJ];
#pragma unroll
  for (int i = 0; i < RI; i++)
#pragma unroll
    for (int j = 0; j < RJ; j++) acc[i][j] = (float4v)0.0f;

  // stage one 64-K tile (BM/32 + BN/32 gl_lds16 per thread)
  auto issue = [&](int k0, char* buf) {
#pragma unroll
    for (int inst = 0; inst < BM / 32; inst++) {
      int p = inst * 256 + tid;
      int r = p >> 3;
      int c = (p & 7) ^ (r & 7);
      gl_lds16(A + (size_t)(m0 + r) * HID + k0 + c * 8, buf + p * 16);
    }
#pragma unroll
    for (int inst = 0; inst < BN / 32; inst++) {
      int p = inst * 256 + tid;
      int r = p >> 3;
      int c = (p & 7) ^ (r & 7);
      gl_lds16(Bt + (size_t)(n0 + r) * HID + k0 + c * 8, buf + BM * 128 + p * 16);
    }
  };

  auto compute = [&](const char* buf) {
#pragma unroll
    for (int kk = 0; kk < 2; kk++) {
      short8 af[RI], bf[RJ];
#pragma unroll
      for (int i = 0; i < RI; i++) {
        int ra = wm * (BM / 2) + i * 16 + l15;
        af[i] = *(const short8*)(buf + ra * 128 + (((kk * 4 + quad) ^ (ra & 7)) * 16));
      }
#pragma unroll
      for (int j = 0; j < RJ; j++) {
        int rb = wn * (BN / 2) + j * 16 + l15;
        bf[j] = *(const short8*)(buf + BM * 128 + rb * 128 + (((kk * 4 + quad) ^ (rb & 7)) * 16));
      }
#pragma unroll
      for (int i = 0; i < RI; i++)
#pragma unroll
        for (int j = 0; j < RJ; j++)
          acc[i][j] = MFMA32(af[i], bf[j], acc[i][j]);
    }
  };

  if (DBUF) {
    constexpr int NLD = BM / 32 + BN / 32;  // vmem loads per thread per tile
    issue(0, lds);
#pragma unroll 1
    for (int t = 0; t < HID / 64; t++) {
      if (t < HID / 64 - 1) {
        issue((t + 1) * 64, lds + ((t + 1) & 1) * TILE);
        asm volatile("s_waitcnt vmcnt(%0)" ::"i"(NLD) : "memory");
      } else {
        asm volatile("s_waitcnt vmcnt(0)" ::: "memory");
      }
      __builtin_amdgcn_s_barrier();
      asm volatile("" ::: "memory");
      compute(lds + (t & 1) * TILE);
      asm volatile("" ::: "memory");
      __builtin_amdgcn_s_barrier();
    }
  } else {
    for (int k0 = 0; k0 < HID; k0 += 64) {
      __syncthreads();
      issue(k0, lds);
      __syncthreads();
      compute(lds);
    }
  }

  if (TRANS_EP && mode == 2) {
    short* eb = (short*)lds;
    __syncthreads();
#pragma unroll
    for (int j = 0; j < RJ; j++) {
      int nl = wn * (BN / 2) + j * 16 + l15;
      float bsv = bias[n0 + nl];
#pragma unroll
      for (int i = 0; i < RI; i++)
#pragma unroll
        for (int r = 0; r < 4; r++) {
          int ml = wm * (BM / 2) + i * 16 + quad * 4 + r;
          eb[nl * VPS + ml] = f2bf(acc[i][j][r] + bsv);
        }
    }
    __syncthreads();
    int row = tid >> 1, half = tid & 1;
    int n = n0 + row, h = n >> 6, d = n & 63;
    int b = m0 >> 11, sc = (m0 & 2047) + half * 64;
    short* dst = outVt + ((size_t)(b * NHEADS + h) * HDIM + d) * S_LEN + sc;
    const short* src = eb + row * VPS + half * 64;
#pragma unroll
    for (int c = 0; c < 8; c++)
      *(short8*)(dst + c * 8) = *(const short8*)(src + c * 8);
    return;
  }

#pragma unroll
  for (int i = 0; i < RI; i++) {
#pragma unroll
    for (int j = 0; j < RJ; j++) {
      int n = n0 + wn * (BN / 2) + j * 16 + l15;
      float bsv = bias[n];
#pragma unroll
      for (int r = 0; r < 4; r++) {
        int m = m0 + wm * (BM / 2) + i * 16 + quad * 4 + r;
        float val = acc[i][j][r] + bsv;
        if (mode == 3) {
          outF[(size_t)m * HID + n] = val;
        } else {
          int b = m >> 11, s = m & 2047, h = n >> 6, d = n & 63;
          if (mode == 1) val *= SCALE_L2E;  // pre-scale K: exp2 arg = dot + maskbias
          short u = f2bf(val);
          if (mode == 0)
            outQ[((size_t)(b * NHEADS + h) * S_LEN + s) * HDIM + d] = u;
          else
            outK[((size_t)(b * NHEADS + h) * S_LEN + s) * HDIM + d] = u;
        }
      }
    }
  }
}

// ---------------- fused attention (r3/r9 structure): key-split waves ------------
// grid (S/64, NH, B), block 256 = 4 waves. Block owns 64 queries; per 128-key
// tile wave w handles keys [w*32, w*32+32). QK^T computed transposed
// (C=K*Q^T) so the 16x16 C-layout IS the 16x16x16 A-layout of P for PV.
// K pre-scaled by log2e/8; accumulator INITIALIZED with mask bias -> bare exp2.
#define ALDS_K 0       // 16KB: K tile [128 keys][64 d] bf16, 16B chunks xor (r&7)
#define ALDS_V 16384   // 16KB: V^T tile [64 d][128 keys] bf16, 16B chunks xor (r&7)
#define ALDS_M 32768   // 8KB: mask bias fp32 [2048] (reused for lrow partials at end)

__device__ __forceinline__ float* buf_addr(float* base, int row, int col) {
  return base + row * 64 + ((((col >> 2) ^ (row & 15)) << 2) | (col & 3));
}

__global__ __launch_bounds__(256, 2) void attn(const short* __restrict__ Qb,
                                               const short* __restrict__ Kb,
                                               const short* __restrict__ Vt,
                                               const float* __restrict__ maskb,
                                               short* __restrict__ ctx) {
  __shared__ __align__(16) char lds[40960];
  const int tid = threadIdx.x, lane = tid & 63, w = tid >> 6;
  const int quad = lane >> 4, l15 = lane & 15;
  const int h = blockIdx.y, b = blockIdx.z, bh = b * NHEADS + h;
  const short* Qh = Qb + (size_t)bh * S_LEN * HDIM;
  const short* Kh = Kb + (size_t)bh * S_LEN * HDIM;
  const short* Vh = Vt + (size_t)bh * HDIM * S_LEN;
  const float* mbase = maskb + b * S_LEN;
  const int qb0 = blockIdx.x * 64;
  const int kw = w * 32;

  // stage mask bias (8KB) once; drained by the first in-loop barrier
#pragma unroll
  for (int inst = 0; inst < 2; inst++) {
    int p = inst * 256 + tid;
    gl_lds16(mbase + p * 4, lds + ALDS_M + p * 16);
  }

  // Q B-frags for all 4 query tiles (held in regs whole kernel)
  short8 qf[4][2];
#pragma unroll
  for (int nt = 0; nt < 4; nt++)
#pragma unroll
    for (int kk = 0; kk < 2; kk++)
      qf[nt][kk] = *(const short8*)(Qh + (size_t)(qb0 + nt * 16 + l15) * HDIM + kk * 32 + quad * 8);

  float4v o[4][4];
#pragma unroll
  for (int nt = 0; nt < 4; nt++)
#pragma unroll
    for (int nd = 0; nd < 4; nd++) o[nt][nd] = (float4v)0.0f;
  float lp[4] = {0.0f, 0.0f, 0.0f, 0.0f};

  for (int kb = 0; kb < S_LEN; kb += 128) {
    __syncthreads();
#pragma unroll
    for (int inst = 0; inst < 4; inst++) {
      int p = inst * 256 + tid;
      int r = p >> 3, c = (p & 7) ^ (r & 7);
      gl_lds16(Kh + (size_t)(kb + r) * HDIM + c * 8, lds + ALDS_K + p * 16);
      int rv = p >> 4, cv = (p & 15) ^ (rv & 7);
      gl_lds16(Vh + (size_t)rv * S_LEN + kb + cv * 8, lds + ALDS_V + p * 16);
    }
    __syncthreads();

    // V B-frags (16x16x16): n=d=l15+16nd, k=key=kw+mt*16+quad*4+j
    short4v bvf[2][4];
#pragma unroll
    for (int mt = 0; mt < 2; mt++) {
      int g = (kw >> 2) + mt * 4 + quad;
      int gc = g >> 1, sub = g & 1;
#pragma unroll
      for (int nd = 0; nd < 4; nd++) {
        int rv = nd * 16 + l15;
        bvf[mt][nd] = *(const short4v*)(lds + ALDS_V + rv * 256 + ((gc ^ (rv & 7)) * 16) + sub * 8);
      }
    }

#pragma unroll
    for (int mt = 0; mt < 2; mt++) {
      int rk = kw + mt * 16 + l15;
      short8 ka0 = *(const short8*)(lds + ALDS_K + rk * 128 + ((quad ^ (rk & 7)) * 16));
      short8 ka1 = *(const short8*)(lds + ALDS_K + rk * 128 + (((4 + quad) ^ (rk & 7)) * 16));
      float4v mbv = *(const float4v*)(lds + ALDS_M + (kb + kw + mt * 16) * 4 + quad * 16);
#pragma unroll
      for (int nt = 0; nt < 4; nt++) {
        float4v c = mbv;  // acc init = mask bias (exp2 domain); K pre-scaled
        c = MFMA32(ka0, qf[nt][0], c);  // C[key][q]
        c = MFMA32(ka1, qf[nt][1], c);
        float4v ev;
#pragma unroll
        for (int r = 0; r < 4; r++) ev[r] = __builtin_amdgcn_exp2f(c[r]);
        lp[nt] += (ev[0] + ev[1]) + (ev[2] + ev[3]);
        short4v ap = pack_bf16x4(ev);
#pragma unroll
        for (int nd = 0; nd < 4; nd++) o[nt][nd] = MFMA16(ap, bvf[mt][nd], o[nt][nd]);
      }
    }
  }

  // ---- epilogue: cross-wave O + lrow reduction through staging LDS ----
#pragma unroll
  for (int nt = 0; nt < 4; nt++) {
    lp[nt] += __shfl_xor(lp[nt], 16, 64);
    lp[nt] += __shfl_xor(lp[nt], 32, 64);
  }
  __syncthreads();
  float* buf0 = (float*)(lds + ALDS_K);
  float* buf1 = (float*)(lds + ALDS_V);
  float* lrowS = (float*)(lds + ALDS_M);
  if (quad == 0) {
#pragma unroll
    for (int nt = 0; nt < 4; nt++) lrowS[w * 64 + nt * 16 + l15] = lp[nt];
  }
  if (w & 1) {
    float* dst = (w == 1) ? buf0 : buf1;
#pragma unroll
    for (int nt = 0; nt < 4; nt++)
#pragma unroll
      for (int nd = 0; nd < 4; nd++)
#pragma unroll
        for (int r = 0; r < 4; r++)
          *buf_addr(dst, nt * 16 + quad * 4 + r, nd * 16 + l15) = o[nt][nd][r];
  }
  __syncthreads();
  if (!(w & 1)) {
    float* srcb = (w == 0) ? buf0 : buf1;
#pragma unroll
    for (int nt = 0; nt < 4; nt++)
#pragma unroll
      for (int nd = 0; nd < 4; nd++)
#pragma unroll
        for (int r = 0; r < 4; r++) {
          float* p = buf_addr(srcb, nt * 16 + quad * 4 + r, nd * 16 + l15);
          *p = *p + o[nt][nd][r];
        }
  }
  __syncthreads();
  int row = w * 16 + l15;
  float ls = lrowS[row] + lrowS[64 + row] + lrowS[128 + row] + lrowS[192 + row];
  float inv = 1.0f / ls;
  short* dstp = ctx + ((size_t)(b * S_LEN + qb0 + row) * HID + h * HDIM + quad * 16);
#pragma unroll
  for (int half = 0; half < 2; half++) {
    int c0 = quad * 16 + half * 8;
    float4v x0 = *(float4v*)buf_addr(buf0, row, c0);
    float4v x1 = *(float4v*)buf_addr(buf0, row, c0 + 4);
    float4v y0 = *(float4v*)buf_addr(buf1, row, c0);
    float4v y1 = *(float4v*)buf_addr(buf1, row, c0 + 4);
    union { short8 s; short4v h[2]; } R;
    float4v s0, s1;
#pragma unroll
    for (int i = 0; i < 4; i++) { s0[i] = (x0[i] + y0[i]) * inv; s1[i] = (x1[i] + y1[i]) * inv; }
    R.h[0] = pack_bf16x4(s0);
    R.h[1] = pack_bf16x4(s1);
    *(short8*)(dstp + half * 8) = R.s;
  }
}

extern "C" void kernel_launch(void* const* d_in, const int* in_sizes, int n_in,
                              void* d_out, int out_size, void* d_ws, size_t ws_size,
                              hipStream_t stream) {
  const float* hs = (const float*)d_in[0];
  const int* mask = (const int*)d_in[1];
  const float* Wq = (const float*)d_in[2];
  const float* bq = (const float*)d_in[3];
  const float* Wk = (const float*)d_in[4];
  const float* bk = (const float*)d_in[5];
  const float* Wv = (const float*)d_in[6];
  const float* bv = (const float*)d_in[7];
  const float* Wo = (const float*)d_in[8];
  const float* bo = (const float*)d_in[9];
  float* out = (float*)d_out;
  char* ws = (char*)d_ws;

  short* XBF = (short*)(ws);
  short* CTX = (short*)(ws);
  short* WT  = (short*)(ws + (size_t)(8u << 20));
  short* QB  = (short*)(ws + (size_t)(16u << 20));
  short* KB  = (short*)(ws + (size_t)(24u << 20));
  short* VTt = (short*)(ws + (size_t)(32u << 20));
  float* MB  = (float*)(ws + (size_t)(40u << 20));

  prep_cast<<<4096, 256, 0, stream>>>(hs, mask, XBF, MB);
  prep_transpose<<<dim3(16, 16, 4), 256, 0, stream>>>(Wq, Wk, Wv, Wo, WT);
  gemm_bt<128, 128, true, true><<<dim3(32, 8, 3), 256, 0, stream>>>(XBF, WT, bq, bk, bv, bo, QB, KB, VTt, nullptr, 0);
  attn<<<dim3(32, NHEADS, BATCH), 256, 0, stream>>>(QB, KB, VTt, MB, CTX);
  gemm_bt<64, 128, false, false><<<dim3(64, 8, 1), 256, 0, stream>>>(CTX, WT, bq, bk, bv, bo, nullptr, nullptr, nullptr, out, 3);
}